// Round 9
// baseline (89.283 us; speedup 1.0000x reference)
//
#include <hip/hip_runtime.h>
#include <math.h>

constexpr int BS = 16;
constexpr int G  = 512;
constexpr int S  = 20;
constexpr int Q  = 256;
constexpr int P  = G * S;                 // 10240
constexpr int NSLICE = 32;                // slices per batch per phase
constexpr int SLICE  = P / NSLICE;        // 320 pred points per slice (= 16 cells)
constexpr int NTASK1 = BS * NSLICE;       // 512 phase-1 wave-tasks (cd1)
constexpr int NTASKS = 2 * NTASK1;        // 1024 waves = 256 producer blocks x 4
constexpr int NPROD  = NTASKS / 4;        // 256 producer blocks
constexpr int NFIN   = BS;                // 16 finalizer blocks (one per batch)
constexpr float THRESHOLD = 0.01f;
constexpr float FARV = 1e15f;             // masked-out pred sentinel (d2 ~ 3e30, finite)
constexpr float FINF = 3.4e38f;

// ws float offsets — ALL pure writes by producers, read only by finalizers
constexpr int WQ  = 0;                    // qpart[BS][NSLICE][Q] d2 = 131072
constexpr int WC1 = WQ + BS * NSLICE * Q; // cd1 partial per phase-1 task [512]
constexpr int WB  = WC1 + NTASK1;         // bce partials [32]
constexpr int WCN = WB + 32;              // masked-cell-count partials [32]

// Completion counter. 0 at module load; each call: producers +256, finalizers +16,
// last finalizer -272 => back to 0 at kernel exit. Same work every call.
__device__ unsigned g_cnt = 0;

// grid = 272 blocks x 256 threads. Blocks [0,256): 4 independent wave-tasks each.
// Blocks [256,272): finalizer for batch (bid-256), spin on g_cnt.
__global__ __launch_bounds__(256) void loss_kernel(
        const float* __restrict__ pred,     // [BS,P,3]
        const float* __restrict__ probs,    // [BS,G]
        const float* __restrict__ gt,       // [BS,Q,3]
        const float* __restrict__ target,   // [BS,G]
        float* __restrict__ ws,
        float* __restrict__ out) {
    const int bid = blockIdx.x;
    const int tid = threadIdx.x;

    if (bid < NPROD) {
        // ================= producer: 4 wave-tasks =================
        const int wid  = tid >> 6;             // wave 0..3 (private LDS region)
        const int l    = tid & 63;
        const int task = bid * 4 + wid;        // 0..1023

        __shared__ float4 sbuf[4][3][80];
        float4* sx4 = sbuf[wid][0];
        float4* sy4 = sbuf[wid][1];
        float4* sz4 = sbuf[wid][2];

        const int phase1 = (task < NTASK1);
        const int id = phase1 ? task : task - NTASK1;
        const int b  = id >> 5;                // /NSLICE
        const int s  = id & (NSLICE - 1);

        if (task == 0 && l == 0) out[0] = 0.0f;   // released before finalizers run

        if (phase1) {
            // ---- cd1: stage 256 gt; own 5 pred points (strided l + 64j) ----
            const float4* gsrc = (const float4*)(gt + (size_t)b * Q * 3);
            float4 a0 = gsrc[3 * l], a1 = gsrc[3 * l + 1], a2 = gsrc[3 * l + 2];
            sx4[l] = make_float4(a0.x, a0.w, a1.z, a2.y);
            sy4[l] = make_float4(a0.y, a1.x, a1.w, a2.z);
            sz4[l] = make_float4(a0.z, a1.y, a2.x, a2.w);

            float oxr[5], oyr[5], ozr[5], om[5];
            const int p0 = s * SLICE + l;
            #pragma unroll
            for (int j = 0; j < 5; ++j) {
                const int p = p0 + 64 * j;
                const float* pp = pred + ((size_t)b * P + p) * 3;
                oxr[j] = pp[0]; oyr[j] = pp[1]; ozr[j] = pp[2];
                om[j] = (probs[b * G + p / S] > THRESHOLD) ? 1.0f : 0.0f;
            }

            float acc[5][4];
            #pragma unroll
            for (int j = 0; j < 5; ++j)
                #pragma unroll
                for (int k = 0; k < 4; ++k) acc[j][k] = FINF;

            #pragma unroll 4
            for (int g = 0; g < 64; ++g) {
                float4 X = sx4[g], Y = sy4[g], Z = sz4[g];   // uniform broadcast
                float gx[4] = {X.x, X.y, X.z, X.w};
                float gy[4] = {Y.x, Y.y, Y.z, Y.w};
                float gz[4] = {Z.x, Z.y, Z.z, Z.w};
                #pragma unroll
                for (int k = 0; k < 4; ++k)
                    #pragma unroll
                    for (int j = 0; j < 5; ++j) {
                        float dx = oxr[j] - gx[k];
                        float dy = oyr[j] - gy[k];
                        float dz = ozr[j] - gz[k];
                        float d  = dx * dx + dy * dy + dz * dz;
                        acc[j][k] = fminf(acc[j][k], d);
                    }
            }
            float contrib = 0.0f;
            #pragma unroll
            for (int j = 0; j < 5; ++j) {
                float mn = fminf(fminf(acc[j][0], acc[j][1]), fminf(acc[j][2], acc[j][3]));
                contrib += om[j] * sqrtf(mn);
            }
            #pragma unroll
            for (int off = 32; off; off >>= 1) contrib += __shfl_down(contrib, off);
            if (l == 0) ws[WC1 + id] = contrib;

            // ---- BCE + mask-cell count folded into tasks 0..31 ----
            if (task < 32) {
                float term = 0.0f, cells = 0.0f;
                #pragma unroll
                for (int j = 0; j < 4; ++j) {
                    int cell = task * 256 + 4 * l + j;
                    float pv = probs[cell];
                    float tv = target[cell];
                    term += -(tv * fmaxf(logf(pv), -100.0f) +
                              (1.0f - tv) * fmaxf(log1pf(-pv), -100.0f));
                    cells += (pv > THRESHOLD) ? 1.0f : 0.0f;
                }
                #pragma unroll
                for (int off = 32; off; off >>= 1) {
                    term  += __shfl_down(term, off);
                    cells += __shfl_down(cells, off);
                }
                if (l == 0) { ws[WB + task] = term; ws[WCN + task] = cells; }
            }
        } else {
            // ---- cd2: stage 320 pred (mask-folded); own 4 gt points ----
            float* sxf = (float*)sx4;
            float* syf = (float*)sy4;
            float* szf = (float*)sz4;
            const int p0 = s * SLICE + l;
            #pragma unroll
            for (int j = 0; j < 5; ++j) {
                const int p = p0 + 64 * j;
                const float* pp = pred + ((size_t)b * P + p) * 3;
                bool m = probs[b * G + p / S] > THRESHOLD;
                sxf[l + 64 * j] = m ? pp[0] : FARV;
                syf[l + 64 * j] = m ? pp[1] : FARV;
                szf[l + 64 * j] = m ? pp[2] : FARV;
            }

            const float4* gsrc = (const float4*)(gt + (size_t)b * Q * 3);
            float4 a0 = gsrc[3 * l], a1 = gsrc[3 * l + 1], a2 = gsrc[3 * l + 2];
            float ogx[4] = {a0.x, a0.w, a1.z, a2.y};
            float ogy[4] = {a0.y, a1.x, a1.w, a2.z};
            float ogz[4] = {a0.z, a1.y, a2.x, a2.w};

            float acc[4][4];
            #pragma unroll
            for (int j = 0; j < 4; ++j)
                #pragma unroll
                for (int k = 0; k < 4; ++k) acc[j][k] = FINF;

            #pragma unroll 4
            for (int g = 0; g < 80; ++g) {
                float4 X = sx4[g], Y = sy4[g], Z = sz4[g];   // uniform broadcast
                float gx[4] = {X.x, X.y, X.z, X.w};
                float gy[4] = {Y.x, Y.y, Y.z, Y.w};
                float gz[4] = {Z.x, Z.y, Z.z, Z.w};
                #pragma unroll
                for (int k = 0; k < 4; ++k)
                    #pragma unroll
                    for (int j = 0; j < 4; ++j) {
                        float dx = ogx[j] - gx[k];
                        float dy = ogy[j] - gy[k];
                        float dz = ogz[j] - gz[k];
                        float d  = dx * dx + dy * dy + dz * dz;
                        acc[j][k] = fminf(acc[j][k], d);
                    }
            }
            float4 v;
            v.x = fminf(fminf(acc[0][0], acc[0][1]), fminf(acc[0][2], acc[0][3]));
            v.y = fminf(fminf(acc[1][0], acc[1][1]), fminf(acc[1][2], acc[1][3]));
            v.z = fminf(fminf(acc[2][0], acc[2][1]), fminf(acc[2][2], acc[2][3]));
            v.w = fminf(fminf(acc[3][0], acc[3][1]), fminf(acc[3][2], acc[3][3]));
            *(float4*)(ws + WQ + (size_t)id * Q + 4 * l) = v;
        }

        // -------- release: all 4 waves' stores drained (syncthreads waits
        // vmcnt(0)), then device-scope fence + signal --------
        __syncthreads();
        if (tid == 0) {
            __threadfence();
            atomicAdd(&g_cnt, 1u);
        }
    } else {
        // ================= finalizer: batch b = bid - NPROD =================
        const int b = bid - NPROD;
        const int t = tid;                    // == q
        __shared__ float sred[4];

        if (t == 0) {
            while (__hip_atomic_load(&g_cnt, __ATOMIC_ACQUIRE,
                                     __HIP_MEMORY_SCOPE_AGENT) < (unsigned)NPROD)
                __builtin_amdgcn_s_sleep(4);
        }
        __syncthreads();
        __threadfence();   // acquire: discard stale cached partials

        const float* qp = ws + WQ + (size_t)b * NSLICE * Q + t;
        float mnv = FINF;
        #pragma unroll
        for (int c = 0; c < NSLICE; ++c) mnv = fminf(mnv, qp[c * Q]);
        float s2 = sqrtf(mnv);

        float s1 = (t < NSLICE) ? ws[WC1 + b * NSLICE + t] : 0.0f;

        #pragma unroll
        for (int off = 32; off; off >>= 1) {
            s2 += __shfl_down(s2, off);
            s1 += __shfl_down(s1, off);
        }
        if ((t & 63) == 0) sred[t >> 6] = s2;   // s1 lives entirely in wave 0
        __syncthreads();

        if (t == 0) {
            float sum2 = sred[0] + sred[1] + sred[2] + sred[3];
            float cnt  = (ws[WCN + 2 * b] + ws[WCN + 2 * b + 1]) * (float)S;
            float cd1  = s1 / fmaxf(cnt, 1.0f);
            float cd2  = sum2 / (float)Q;
            float cdb  = (cnt > 0.0f) ? fmaxf(cd1, cd2) : 0.0f;
            atomicAdd(out, cdb / (float)BS);
        }
        // finalizer for batch 0: BCE sum on wave 1
        if (b == 0 && t >= 64 && t < 128) {
            int l = t - 64;
            float bb = (l < 32) ? ws[WB + l] : 0.0f;
            #pragma unroll
            for (int off = 32; off; off >>= 1) bb += __shfl_down(bb, off);
            if (l == 0) atomicAdd(out, bb / (float)(BS * G));
        }

        // -------- self-resetting counter: +1 per finalizer; last subtracts 272 --------
        __syncthreads();
        if (t == 0) {
            unsigned old = atomicAdd(&g_cnt, 1u);
            if (old == (unsigned)(NPROD + NFIN - 1))
                atomicSub(&g_cnt, (unsigned)(NPROD + NFIN));
        }
    }
}

extern "C" void kernel_launch(void* const* d_in, const int* in_sizes, int n_in,
                              void* d_out, int out_size, void* d_ws, size_t ws_size,
                              hipStream_t stream) {
    const float* diff_pred   = (const float*)d_in[0];
    const float* probs_pred  = (const float*)d_in[1];
    const float* diff_gt     = (const float*)d_in[2];
    const float* prob_target = (const float*)d_in[3];
    float* out = (float*)d_out;
    float* ws  = (float*)d_ws;

    loss_kernel<<<NPROD + NFIN, 256, 0, stream>>>(
        diff_pred, probs_pred, diff_gt, prob_target, ws, out);
}

// Round 11
// 81.209 us; speedup vs baseline: 1.0994x; 1.0994x over previous
//
#include <hip/hip_runtime.h>
#include <math.h>

constexpr int BS = 16;
constexpr int G  = 512;
constexpr int S  = 20;
constexpr int Q  = 256;
constexpr int P  = G * S;                 // 10240
constexpr int NSLICE = 32;                // slices per batch per phase
constexpr int SLICE  = P / NSLICE;        // 320 pred points per slice (= 16 cells)
constexpr int NTASK1 = BS * NSLICE;       // 512 phase-1 wave-tasks (cd1)
constexpr int NTASKS = 2 * NTASK1;        // 1024 waves = 256 blocks x 4 = 1 wave/SIMD
constexpr float THRESHOLD = 0.01f;
constexpr float FARV = 1e15f;             // masked-out pred sentinel (d2 ~ 3e30, finite)
constexpr float FINF = 3.4e38f;

// ws float offsets — ALL pure writes, read only by finalize (no init needed)
constexpr int WQ  = 0;                    // qpart[BS][NSLICE][Q] d2 = 131072
constexpr int WC1 = WQ + BS * NSLICE * Q; // cd1 partial per phase-1 task [512]
constexpr int WB  = WC1 + NTASK1;         // bce partials [32]
constexpr int WCN = WB + 32;              // masked-cell-count partials [32]

// 256 blocks x 256 threads. Blocks [0,128): phase-1 (4 slices of one batch, shared
// gt staging). Blocks [128,256): phase-2 (4 independent pred-slice wave-tasks).
__global__ __launch_bounds__(256) void chamfer_kernel(
        const float* __restrict__ pred,     // [BS,P,3]
        const float* __restrict__ probs,    // [BS,G]
        const float* __restrict__ gt,       // [BS,Q,3]
        const float* __restrict__ target,   // [BS,G]
        float* __restrict__ ws,
        float* __restrict__ out) {
    const int bid  = blockIdx.x;
    const int tid  = threadIdx.x;
    const int wid  = tid >> 6;               // wave 0..3
    const int l    = tid & 63;
    const int task = bid * 4 + wid;          // 0..1023

    __shared__ float4 sbuf[4][3][80];        // phase-2: private per wave; phase-1: sbuf[0] shared

    const bool blk_phase1 = (bid * 4 < NTASK1);
    const int id = blk_phase1 ? task : task - NTASK1;
    const int b  = id >> 5;                  // /NSLICE (uniform within block)
    const int s  = id & (NSLICE - 1);

    if (task == 0 && l == 0) out[0] = 0.0f;  // flushed at kernel boundary, pre-finalize

    if (blk_phase1) {
        // ---- cd1: block-shared gt staging (wave 0 only); own 5 pred pts/lane ----
        float4* sx4 = sbuf[0][0];
        float4* sy4 = sbuf[0][1];
        float4* sz4 = sbuf[0][2];
        if (tid < 64) {
            const float4* gsrc = (const float4*)(gt + (size_t)b * Q * 3);
            float4 a0 = gsrc[3 * l], a1 = gsrc[3 * l + 1], a2 = gsrc[3 * l + 2];
            sx4[l] = make_float4(a0.x, a0.w, a1.z, a2.y);
            sy4[l] = make_float4(a0.y, a1.x, a1.w, a2.z);
            sz4[l] = make_float4(a0.z, a1.y, a2.x, a2.w);
        }

        float oxr[5], oyr[5], ozr[5], om[5];
        const int p0 = s * SLICE + l;
        #pragma unroll
        for (int j = 0; j < 5; ++j) {
            const int p = p0 + 64 * j;
            const float* pp = pred + ((size_t)b * P + p) * 3;
            oxr[j] = pp[0]; oyr[j] = pp[1]; ozr[j] = pp[2];
            om[j] = (probs[b * G + p / S] > THRESHOLD) ? 1.0f : 0.0f;
        }
        __syncthreads();

        float acc[5][4];
        #pragma unroll
        for (int j = 0; j < 5; ++j)
            #pragma unroll
            for (int k = 0; k < 4; ++k) acc[j][k] = FINF;

        #pragma unroll 4
        for (int g = 0; g < 64; ++g) {
            float4 X = sx4[g], Y = sy4[g], Z = sz4[g];   // uniform broadcast
            float gx[4] = {X.x, X.y, X.z, X.w};
            float gy[4] = {Y.x, Y.y, Y.z, Y.w};
            float gz[4] = {Z.x, Z.y, Z.z, Z.w};
            #pragma unroll
            for (int k = 0; k < 4; ++k)
                #pragma unroll
                for (int j = 0; j < 5; ++j) {
                    float dx = oxr[j] - gx[k];
                    float dy = oyr[j] - gy[k];
                    float dz = ozr[j] - gz[k];
                    float d  = dx * dx + dy * dy + dz * dz;
                    acc[j][k] = fminf(acc[j][k], d);
                }
        }
        float contrib = 0.0f;
        #pragma unroll
        for (int j = 0; j < 5; ++j) {
            float mn = fminf(fminf(acc[j][0], acc[j][1]), fminf(acc[j][2], acc[j][3]));
            contrib += om[j] * sqrtf(mn);
        }
        #pragma unroll
        for (int off = 32; off; off >>= 1) contrib += __shfl_down(contrib, off);
        if (l == 0) ws[WC1 + id] = contrib;

        // ---- BCE + mask-cell count folded into tasks 0..31 (256 cells each) ----
        if (task < 32) {
            float term = 0.0f, cells = 0.0f;
            #pragma unroll
            for (int j = 0; j < 4; ++j) {
                int cell = task * 256 + 4 * l + j;
                float pv = probs[cell];
                float tv = target[cell];
                term += -(tv * fmaxf(logf(pv), -100.0f) +
                          (1.0f - tv) * fmaxf(log1pf(-pv), -100.0f));
                cells += (pv > THRESHOLD) ? 1.0f : 0.0f;
            }
            #pragma unroll
            for (int off = 32; off; off >>= 1) {
                term  += __shfl_down(term, off);
                cells += __shfl_down(cells, off);
            }
            if (l == 0) { ws[WB + task] = term; ws[WCN + task] = cells; }
        }
    } else {
        // ---- cd2: each wave stages its 320-pred slice (mask-folded); own 4 gt ----
        float* sxf = (float*)sbuf[wid][0];
        float* syf = (float*)sbuf[wid][1];
        float* szf = (float*)sbuf[wid][2];
        const int p0 = s * SLICE + l;
        #pragma unroll
        for (int j = 0; j < 5; ++j) {
            const int p = p0 + 64 * j;
            const float* pp = pred + ((size_t)b * P + p) * 3;
            bool m = probs[b * G + p / S] > THRESHOLD;
            sxf[l + 64 * j] = m ? pp[0] : FARV;
            syf[l + 64 * j] = m ? pp[1] : FARV;
            szf[l + 64 * j] = m ? pp[2] : FARV;
        }

        const float4* gsrc = (const float4*)(gt + (size_t)b * Q * 3);
        float4 a0 = gsrc[3 * l], a1 = gsrc[3 * l + 1], a2 = gsrc[3 * l + 2];
        float ogx[4] = {a0.x, a0.w, a1.z, a2.y};
        float ogy[4] = {a0.y, a1.x, a1.w, a2.z};
        float ogz[4] = {a0.z, a1.y, a2.x, a2.w};

        const float4* sx4 = sbuf[wid][0];
        const float4* sy4 = sbuf[wid][1];
        const float4* sz4 = sbuf[wid][2];

        float acc[4][4];
        #pragma unroll
        for (int j = 0; j < 4; ++j)
            #pragma unroll
            for (int k = 0; k < 4; ++k) acc[j][k] = FINF;

        #pragma unroll 4
        for (int g = 0; g < 80; ++g) {
            float4 X = sx4[g], Y = sy4[g], Z = sz4[g];   // uniform broadcast
            float gx[4] = {X.x, X.y, X.z, X.w};
            float gy[4] = {Y.x, Y.y, Y.z, Y.w};
            float gz[4] = {Z.x, Z.y, Z.z, Z.w};
            #pragma unroll
            for (int k = 0; k < 4; ++k)
                #pragma unroll
                for (int j = 0; j < 4; ++j) {
                    float dx = ogx[j] - gx[k];
                    float dy = ogy[j] - gy[k];
                    float dz = ogz[j] - gz[k];
                    float d  = dx * dx + dy * dy + dz * dz;
                    acc[j][k] = fminf(acc[j][k], d);
                }
        }
        float4 v;
        v.x = fminf(fminf(acc[0][0], acc[0][1]), fminf(acc[0][2], acc[0][3]));
        v.y = fminf(fminf(acc[1][0], acc[1][1]), fminf(acc[1][2], acc[1][3]));
        v.z = fminf(fminf(acc[2][0], acc[2][1]), fminf(acc[2][2], acc[2][3]));
        v.w = fminf(fminf(acc[3][0], acc[3][1]), fminf(acc[3][2], acc[3][3]));
        // pure coalesced float4 store of this slice's per-gt min d2
        *(float4*)(ws + WQ + (size_t)id * Q + 4 * l) = v;
    }
}

// grid = 16 blocks x 256 threads; block b handles batch b.
// Thread q: min over 32 slice partials (coalesced, independent loads), sqrt, sum.
__global__ __launch_bounds__(256) void finalize_kernel(
        const float* __restrict__ ws, float* __restrict__ out) {
    const int b = blockIdx.x;
    const int t = threadIdx.x;              // == q
    __shared__ float sred[4];

    const float* qp = ws + WQ + (size_t)b * NSLICE * Q + t;
    float mnv = FINF;
    #pragma unroll
    for (int c = 0; c < NSLICE; ++c) mnv = fminf(mnv, qp[c * Q]);
    float s2 = sqrtf(mnv);

    // cd1 partials (threads 0..31) folded into the same reduction lanes
    float s1 = (t < NSLICE) ? ws[WC1 + b * NSLICE + t] : 0.0f;

    #pragma unroll
    for (int off = 32; off; off >>= 1) {
        s2 += __shfl_down(s2, off);
        s1 += __shfl_down(s1, off);
    }
    if ((t & 63) == 0) sred[t >> 6] = s2;   // s1 lives entirely in wave 0
    __syncthreads();

    if (t == 0) {
        float sum2 = sred[0] + sred[1] + sred[2] + sred[3];
        float cnt  = (ws[WCN + 2 * b] + ws[WCN + 2 * b + 1]) * (float)S;
        float cd1  = s1 / fmaxf(cnt, 1.0f);
        float cd2  = sum2 / (float)Q;
        float cdb  = (cnt > 0.0f) ? fmaxf(cd1, cd2) : 0.0f;
        atomicAdd(out, cdb / (float)BS);
    }
    // block 0, wave 1: BCE sum (32 partials)
    if (b == 0 && t >= 64 && t < 128) {
        int l = t - 64;
        float bb = (l < 32) ? ws[WB + l] : 0.0f;
        #pragma unroll
        for (int off = 32; off; off >>= 1) bb += __shfl_down(bb, off);
        if (l == 0) atomicAdd(out, bb / (float)(BS * G));
    }
}

extern "C" void kernel_launch(void* const* d_in, const int* in_sizes, int n_in,
                              void* d_out, int out_size, void* d_ws, size_t ws_size,
                              hipStream_t stream) {
    const float* diff_pred   = (const float*)d_in[0];
    const float* probs_pred  = (const float*)d_in[1];
    const float* diff_gt     = (const float*)d_in[2];
    const float* prob_target = (const float*)d_in[3];
    float* out = (float*)d_out;
    float* ws  = (float*)d_ws;

    chamfer_kernel<<<NTASKS / 4, 256, 0, stream>>>(
        diff_pred, probs_pred, diff_gt, prob_target, ws, out);
    finalize_kernel<<<BS, 256, 0, stream>>>(ws, out);
}